// Round 1
// baseline (1217.690 us; speedup 1.0000x reference)
//
#include <hip/hip_runtime.h>
#include <hip/hip_bf16.h>

#define Bn 4
#define C1n 256
#define C2n 128
#define CF 384
#define Hn 256
#define Wn 256
#define HWn 65536
#define Kc 128
#define Nn 512          // B*K
#define En 256
#define NCn 16
#define Gn 512
#define Rn 64
#define HEADSn 8
#define DHn 32

// ---------------- area histogram: one block per batch ----------------
__global__ void area_k(const int* __restrict__ mask, float* __restrict__ areaf,
                       float* __restrict__ area_out) {
    int b = blockIdx.x;
    __shared__ int hist[132];
    for (int i = threadIdx.x; i < 132; i += blockDim.x) hist[i] = 0;
    __syncthreads();
    const int* mp = mask + (size_t)b * HWn;
    for (int px = threadIdx.x * 4; px < HWn; px += blockDim.x * 4) {
        int4 id = *(const int4*)(mp + px);
        atomicAdd(&hist[id.x], 1);
        atomicAdd(&hist[id.y], 1);
        atomicAdd(&hist[id.z], 1);
        atomicAdd(&hist[id.w], 1);
    }
    __syncthreads();
    int t = threadIdx.x;
    if (t >= 1 && t <= Kc) {
        float a = (float)hist[t];
        areaf[b * Kc + t - 1] = a;
        area_out[b * Kc + t - 1] = a;
    }
}

// ---------------- segment reduce: one block per (batch, channel) ----------------
__global__ void segreduce_k(const float* __restrict__ hd1, const float* __restrict__ h1,
                            const int* __restrict__ mask,
                            float* __restrict__ sums, float* __restrict__ glob) {
    int bc = blockIdx.x;            // 0 .. B*CF-1
    int b = bc / CF;
    int c = bc % CF;
    const float* plane = (c < C1n) ? hd1 + ((size_t)(b * C1n + c)) * HWn
                                   : h1 + ((size_t)(b * C2n + (c - C1n))) * HWn;
    const int* mp = mask + (size_t)b * HWn;
    __shared__ float bins[4][132];
    __shared__ float stot[132];
    int wave = threadIdx.x >> 6;
    for (int i = threadIdx.x; i < 4 * 132; i += blockDim.x) ((float*)bins)[i] = 0.f;
    __syncthreads();
    float* mybins = bins[wave];
    for (int px = threadIdx.x * 4; px < HWn; px += blockDim.x * 4) {
        float4 v = *(const float4*)(plane + px);
        int4 id = *(const int4*)(mp + px);
        atomicAdd(&mybins[id.x], v.x);
        atomicAdd(&mybins[id.y], v.y);
        atomicAdd(&mybins[id.z], v.z);
        atomicAdd(&mybins[id.w], v.w);
    }
    __syncthreads();
    int t = threadIdx.x;
    if (t < 129) {
        float s = bins[0][t] + bins[1][t] + bins[2][t] + bins[3][t];
        stot[t] = s;
        if (t >= 1) sums[(size_t)(b * Kc + t - 1) * CF + c] = s;
    }
    __syncthreads();
    if (t == 0) {
        float tot = 0.f;
        for (int i = 0; i < 129; i++) tot += stot[i];
        glob[b * CF + c] = tot * (1.f / (float)HWn);
    }
}

// ---------------- emb GEMM: A built on the fly, [512,768]x[768,256] ----------------
__global__ void gemm_emb_k(const float* __restrict__ sums, const float* __restrict__ glob,
                           const float* __restrict__ areaf, const float* __restrict__ Bw,
                           float* __restrict__ C) {
    const int R = 4, K = 768, N = 256;
    int row0 = blockIdx.x * R;
    __shared__ float As[R * K];
    __shared__ float rina[R];
    if (threadIdx.x < R) {
        float a = areaf[row0 + threadIdx.x];
        rina[threadIdx.x] = 1.f / fmaxf(a, 1.f);
    }
    __syncthreads();
    for (int idx = threadIdx.x; idx < R * K; idx += blockDim.x) {
        int r = idx / K, k = idx % K;
        int row = row0 + r;
        float v;
        if (k < CF) v = sums[(size_t)row * CF + k] * rina[r];
        else        v = glob[(row >> 7) * CF + (k - CF)];
        As[r * K + k] = v;
    }
    __syncthreads();
    int j = threadIdx.x;
    float acc[R] = {0.f, 0.f, 0.f, 0.f};
    const float* bp = Bw + j;
    #pragma unroll 8
    for (int k = 0; k < K; k++) {
        float bv = bp[(size_t)k * N];
        #pragma unroll
        for (int r = 0; r < R; r++) acc[r] = fmaf(As[r * K + k], bv, acc[r]);
    }
    #pragma unroll
    for (int r = 0; r < R; r++) C[(size_t)(row0 + r) * N + j] = acc[r];
}

// ---------------- generic batched row-strip GEMM ----------------
template <int R, bool RELU>
__global__ void gemm_rows_k(const float* __restrict__ A, long long sA,
                            const float* __restrict__ Bw, long long sB,
                            float* __restrict__ C, long long sC,
                            int M, int N, int K) {
    int i = blockIdx.y;
    A += (size_t)i * sA; Bw += (size_t)i * sB; C += (size_t)i * sC;
    int row0 = blockIdx.x * R;
    extern __shared__ float As[];
    for (int idx = threadIdx.x; idx < R * K; idx += blockDim.x)
        As[idx] = A[(size_t)(row0 + idx / K) * K + (idx % K)];
    __syncthreads();
    for (int j = threadIdx.x; j < N; j += blockDim.x) {
        float acc[R];
        #pragma unroll
        for (int r = 0; r < R; r++) acc[r] = 0.f;
        const float* bp = Bw + j;
        #pragma unroll 8
        for (int k = 0; k < K; k++) {
            float bv = bp[(size_t)k * N];
            #pragma unroll
            for (int r = 0; r < R; r++) acc[r] = fmaf(As[r * K + k], bv, acc[r]);
        }
        #pragma unroll
        for (int r = 0; r < R; r++) {
            float v = acc[r];
            if (RELU) v = fmaxf(v, 0.f);
            C[(size_t)(row0 + r) * N + j] = v;
        }
    }
}

// ---------------- per-batch mean of emb over K cells ----------------
__global__ void patch_mean_k(const float* __restrict__ emb, float* __restrict__ ep) {
    int b = blockIdx.x, j = threadIdx.x;
    float s = 0.f;
    for (int r = 0; r < Kc; r++) s += emb[(size_t)(b * Kc + r) * En + j];
    ep[b * En + j] = s * (1.f / (float)Kc);
}

// ---------------- comp MLP + softmax: one block per batch ----------------
__global__ void comp_mlp_k(const float* __restrict__ ep, const float* __restrict__ w1,
                           const float* __restrict__ w2, float* __restrict__ comp_ws,
                           float* __restrict__ comp_out) {
    int b = blockIdx.x, j = threadIdx.x;
    __shared__ float h[En];
    __shared__ float c[NCn];
    float acc = 0.f;
    #pragma unroll 8
    for (int k = 0; k < En; k++) acc = fmaf(ep[b * En + k], w1[(size_t)k * En + j], acc);
    h[j] = fmaxf(acc, 0.f);
    __syncthreads();
    if (j < NCn) {
        float a2 = 0.f;
        #pragma unroll 8
        for (int k = 0; k < En; k++) a2 = fmaf(h[k], w2[(size_t)k * NCn + j], a2);
        c[j] = a2;
    }
    __syncthreads();
    if (j == 0) {
        float m = c[0];
        for (int t = 1; t < NCn; t++) m = fmaxf(m, c[t]);
        float s = 0.f;
        for (int t = 0; t < NCn; t++) { c[t] = __expf(c[t] - m); s += c[t]; }
        float inv = 1.f / s;
        for (int t = 0; t < NCn; t++) c[t] *= inv;
    }
    __syncthreads();
    if (j < NCn) {
        comp_ws[b * NCn + j] = c[j];
        comp_out[b * NCn + j] = c[j];
    }
}

// ---------------- row softmax over 64 cols, one wave per row ----------------
__global__ void softmax64_k(float* __restrict__ X) {
    size_t row = (size_t)blockIdx.y * Nn + blockIdx.x;
    float v = X[row * Rn + threadIdx.x];
    float m = v;
    #pragma unroll
    for (int o = 32; o > 0; o >>= 1) m = fmaxf(m, __shfl_xor(m, o));
    float e = __expf(v - m);
    float s = e;
    #pragma unroll
    for (int o = 32; o > 0; o >>= 1) s += __shfl_xor(s, o);
    X[row * Rn + threadIdx.x] = e / s;
}

// ---------------- collapsed attention: q rows repeat per batch ----------------
// grid.x = HEADS*B (b = x&3, h = x>>2), grid.y = branch
__global__ void attn_k(const float* __restrict__ compw, const float* __restrict__ wq,
                       const float* __restrict__ kmat, const float* __restrict__ vmat,
                       float* __restrict__ o4) {
    int i = blockIdx.y;
    int b = blockIdx.x & 3, h = blockIdx.x >> 2;
    const float* wqi = wq + (size_t)i * NCn * En;
    const float* km = kmat + (size_t)i * Nn * En;
    const float* vm = vmat + (size_t)i * Nn * En;
    __shared__ float q[DHn];
    __shared__ float p[Nn];
    __shared__ float red[4];
    int t = threadIdx.x;
    if (t < DHn) {
        float acc = 0.f;
        #pragma unroll
        for (int c = 0; c < NCn; c++)
            acc = fmaf(compw[b * NCn + c], wqi[(size_t)c * En + h * DHn + t], acc);
        q[t] = acc;
    }
    __syncthreads();
    const float scale = 0.17677669529663687f; // 1/sqrt(32)
    float sv[2];
    #pragma unroll
    for (int rep = 0; rep < 2; rep++) {
        int j = t + rep * 256;
        float acc = 0.f;
        const float* kr = km + (size_t)j * En + h * DHn;
        #pragma unroll
        for (int d = 0; d < DHn; d++) acc = fmaf(q[d], kr[d], acc);
        sv[rep] = acc * scale;
        p[j] = sv[rep];
    }
    __syncthreads();
    float lm = fmaxf(sv[0], sv[1]);
    #pragma unroll
    for (int o = 32; o > 0; o >>= 1) lm = fmaxf(lm, __shfl_xor(lm, o));
    if ((t & 63) == 0) red[t >> 6] = lm;
    __syncthreads();
    float m = fmaxf(fmaxf(red[0], red[1]), fmaxf(red[2], red[3]));
    __syncthreads();           // everyone has read red before it is overwritten
    float ls = 0.f;
    #pragma unroll
    for (int rep = 0; rep < 2; rep++) {
        int j = t + rep * 256;
        float e = __expf(p[j] - m);
        p[j] = e;
        ls += e;
    }
    #pragma unroll
    for (int o = 32; o > 0; o >>= 1) ls += __shfl_xor(ls, o);
    if ((t & 63) == 0) red[t >> 6] = ls;
    __syncthreads();
    float s = red[0] + red[1] + red[2] + red[3];
    if (t < DHn) {
        float acc = 0.f;
        for (int j = 0; j < Nn; j++)
            acc = fmaf(p[j], vm[(size_t)j * En + h * DHn + t], acc);
        o4[((size_t)i * Bn + b) * En + h * DHn + t] = acc / s;
    }
}

// ---------------- out_exprs = relu(refw + ow[batch]) ----------------
__global__ void add_relu_k(const float* __restrict__ refw, const float* __restrict__ ow,
                           float* __restrict__ out) {
    int i = blockIdx.y, n = blockIdx.x, b = n >> 7;
    const float* rr = refw + ((size_t)i * Nn + n) * Gn;
    const float* oo = ow + ((size_t)i * Bn + b) * Gn;
    float* op = out + (size_t)i * (Nn * Gn) + (size_t)n * Gn;
    for (int j = threadIdx.x; j < Gn; j += blockDim.x)
        op[j] = fmaxf(rr[j] + oo[j], 0.f);
}

extern "C" void kernel_launch(void* const* d_in, const int* in_sizes, int n_in,
                              void* d_out, int out_size, void* d_ws, size_t ws_size,
                              hipStream_t stream) {
    const float* hd1     = (const float*)d_in[0];
    const float* h1      = (const float*)d_in[1];
    const float* ref     = (const float*)d_in[2];
    const float* embed_w = (const float*)d_in[3];
    const float* comp_w1 = (const float*)d_in[4];
    const float* comp_w2 = (const float*)d_in[5];
    const float* hist_w1 = (const float*)d_in[6];
    const float* hist_w2 = (const float*)d_in[7];
    const float* genes_w1= (const float*)d_in[8];
    const float* genes_w2= (const float*)d_in[9];
    const float* wref_w1 = (const float*)d_in[10];
    const float* wref_w2 = (const float*)d_in[11];
    const float* ca_wq   = (const float*)d_in[12];
    const float* ca_wk   = (const float*)d_in[13];
    const float* ca_wv   = (const float*)d_in[14];
    const float* ca_wo   = (const float*)d_in[15];
    const int*   mask    = (const int*)d_in[16];

    float* out = (float*)d_out;
    // output offsets (floats)
    const size_t o_ct   = 0;                   // [512,16]
    const size_t o_e0   = 8192;                // [512,512] x3
    const size_t o_octe = 8192 + 3 * 262144;   // 794624, [512,16]
    const size_t o_gh   = o_octe + 8192;       // 802816, [512,256]
    const size_t o_comp = o_gh + 131072;       // 933888, [4,16]
    const size_t o_area = o_comp + 64;         // 933952, [512]

    // workspace layout (floats)
    float* ws      = (float*)d_ws;
    float* sums    = ws;                     // 512*384
    float* glob    = sums + 196608;          // 4*384
    float* areaf   = glob + 1536;            // 512
    float* emb     = areaf + 512;            // 512*256
    float* ep      = emb + 131072;           // 4*256
    float* compw   = ep + 1024;              // 4*16
    float* hist_h  = compw + 64;             // 512*256
    float* tmpT    = hist_h + 131072;        // 3*512*256
    float* rwl     = tmpT + 393216;          // 3*512*64
    float* refw    = rwl + 98304;            // 3*512*512
    float* kws     = refw + 786432;          // 3*512*256
    float* vws     = kws + 393216;           // 3*512*256
    float* o4      = vws + 393216;           // 3*4*256
    float* ow      = o4 + 3072;              // 3*4*512

    area_k<<<Bn, 256, 0, stream>>>(mask, areaf, out + o_area);
    segreduce_k<<<Bn * CF, 256, 0, stream>>>(hd1, h1, mask, sums, glob);
    gemm_emb_k<<<Nn / 4, 256, 0, stream>>>(sums, glob, areaf, embed_w, emb);
    patch_mean_k<<<Bn, 256, 0, stream>>>(emb, ep);
    comp_mlp_k<<<Bn, 256, 0, stream>>>(ep, comp_w1, comp_w2, compw, out + o_comp);

    // out_cell_type = relu(emb @ hist_w1) @ hist_w2
    gemm_rows_k<4, true ><<<dim3(Nn / 4, 1), 256, 4 * 256 * 4, stream>>>(
        emb, 0, hist_w1, 0, hist_h, 0, Nn, En, En);
    gemm_rows_k<4, false><<<dim3(Nn / 4, 1), 256, 4 * 256 * 4, stream>>>(
        hist_h, 0, hist_w2, 0, out + o_ct, 0, Nn, NCn, En);

    // branches (batched over blockIdx.y = 3)
    gemm_rows_k<4, true ><<<dim3(Nn / 4, 3), 256, 4 * 256 * 4, stream>>>(
        emb, 0, wref_w1, (long long)En * En, tmpT, (long long)Nn * En, Nn, En, En);
    gemm_rows_k<4, false><<<dim3(Nn / 4, 3), 256, 4 * 256 * 4, stream>>>(
        tmpT, (long long)Nn * En, wref_w2, (long long)En * Rn, rwl, (long long)Nn * Rn, Nn, Rn, En);
    softmax64_k<<<dim3(Nn, 3), 64, 0, stream>>>(rwl);
    gemm_rows_k<4, false><<<dim3(Nn / 4, 3), 256, 4 * 64 * 4, stream>>>(
        rwl, (long long)Nn * Rn, ref, 0, refw, (long long)Nn * Gn, Nn, Gn, Rn);
    gemm_rows_k<4, false><<<dim3(Nn / 4, 3), 256, 4 * 512 * 4, stream>>>(
        refw, (long long)Nn * Gn, ca_wk, (long long)Gn * En, kws, (long long)Nn * En, Nn, En, Gn);
    gemm_rows_k<4, false><<<dim3(Nn / 4, 3), 256, 4 * 512 * 4, stream>>>(
        refw, (long long)Nn * Gn, ca_wv, (long long)Gn * En, vws, (long long)Nn * En, Nn, En, Gn);
    attn_k<<<dim3(HEADSn * Bn, 3), 256, 0, stream>>>(compw, ca_wq, kws, vws, o4);
    gemm_rows_k<4, false><<<dim3(1, 3), 256, 4 * 256 * 4, stream>>>(
        o4, (long long)Bn * En, ca_wo, (long long)En * Gn, ow, (long long)Bn * Gn, Bn, Gn, En);
    add_relu_k<<<dim3(Nn, 3), 256, 0, stream>>>(refw, ow, out + o_e0);

    // genes_h = relu(out_exprs[0] @ genes_w1); out_cell_type_expr = genes_h @ genes_w2
    gemm_rows_k<4, true ><<<dim3(Nn / 4, 1), 256, 4 * 512 * 4, stream>>>(
        out + o_e0, 0, genes_w1, 0, out + o_gh, 0, Nn, En, Gn);
    gemm_rows_k<4, false><<<dim3(Nn / 4, 1), 256, 4 * 256 * 4, stream>>>(
        out + o_gh, 0, genes_w2, 0, out + o_octe, 0, Nn, NCn, En);
}